// Round 9
// baseline (108.601 us; speedup 1.0000x reference)
//
#include <hip/hip_runtime.h>

#define B_   8
#define N_   307
#define BN   (B_ * N_)          // 2456 blocks
#define OUT_ELEMS (BN * 64 * 64)

typedef float f32x4 __attribute__((ext_vector_type(4)));
typedef short s16x8 __attribute__((ext_vector_type(8)));
typedef unsigned int u32x4 __attribute__((ext_vector_type(4)));

__device__ __forceinline__ unsigned short f2bf(float x) {
    unsigned int u = __builtin_bit_cast(unsigned int, x);
    u += 0x7FFFu + ((u >> 16) & 1u);        // round-to-nearest-even
    return (unsigned short)(u >> 16);
}

// XOR-swizzle on 16B frag rows (G4 / m201): bijective within 8-row groups.
__device__ __forceinline__ int swz(int row) { return row ^ ((row >> 3) & 7); }

__device__ __forceinline__ s16x8 ldfrag(const unsigned short* p) {
    return *reinterpret_cast<const s16x8*>(p);
}

__device__ __forceinline__ s16x8 cvt8(float4 lo, float4 hi) {
    s16x8 f;
    f[0] = (short)f2bf(lo.x); f[1] = (short)f2bf(lo.y);
    f[2] = (short)f2bf(lo.z); f[3] = (short)f2bf(lo.w);
    f[4] = (short)f2bf(hi.x); f[5] = (short)f2bf(hi.y);
    f[6] = (short)f2bf(hi.z); f[7] = (short)f2bf(hi.w);
    return f;
}

// 64x64 row-major fp32 (K x N) global -> bf16 B-operand frag layout (swizzled)
__device__ __forceinline__ void stage_B(const float* __restrict__ src,
                                        unsigned short* dst, int tid) {
    const float4* s4 = reinterpret_cast<const float4*>(src);
#pragma unroll
    for (int i = 0; i < 4; ++i) {
        int idx = i * 256 + tid;
        float4 v = s4[idx];
        int k  = idx >> 4;
        int n0 = (idx & 15) << 2;
        int ki = k >> 5;
        int qd = (k >> 3) & 3;
        int j  = k & 7;
        float vv[4] = {v.x, v.y, v.z, v.w};
#pragma unroll
        for (int c = 0; c < 4; ++c) {
            int n = n0 + c;
            int row = ((n >> 4) * 2 + ki) * 64 + (qd << 4) + (n & 15);
            dst[(swz(row) << 3) + j] = f2bf(vv[c]);
        }
    }
}

__global__ __launch_bounds__(256, 4) void mta_kernel(
    const float* __restrict__ Xq, const float* __restrict__ Xk,
    const float* __restrict__ Xv, const float* __restrict__ maskp,
    const float* __restrict__ res, const float* __restrict__ Wq,
    const float* __restrict__ Wk, const float* __restrict__ Wv,
    const float* __restrict__ Wfc, const float* __restrict__ lnS,
    const float* __restrict__ lnB, float* __restrict__ out,
    float* __restrict__ scores_out)
{
    // 26KB LDS (24KB frags + dedicated 2KB double-buffered wS) -> 6 blocks/CU
    // if VGPR <= 85. Q frags in registers (operand-swapped proj + 4 shfl/head).
    // Barrier-drain engineering (this round's change):
    //  - score stores DEFERRED past the combine barrier -> drain at the NEXT
    //    head's barrier (full head of runway);
    //  - next head's res loads issued right AFTER the barrier -> never drained
    //    by a barrier; residual wait is per-wave at next QK (overlappable);
    //  - dedicated wS kills the h0 aliasing barrier.
    __shared__ __align__(16) unsigned char smem[26624];
    unsigned short* sKf = (unsigned short*)(smem);           // 8KB scores B-frags (K) / ctx frags (fc)
    unsigned short* sVf = (unsigned short*)(smem + 8192);    // 8KB PV B-frags (V)
    unsigned short* sWA = (unsigned short*)(smem + 16384);   // 8KB W frags / attn A-frags
    // smem+24576: 2x1KB wS column-sum buffers (double-buffered by h&1)

    const int bn   = blockIdx.x;
    const int tid  = threadIdx.x;
    const int w    = tid >> 6;
    const int lane = tid & 63;
    const int quad = lane >> 4;
    const int l16  = lane & 15;
    const size_t base64 = (size_t)bn * 4096;

    // q-tiled per-lane tile offset: element (q = w*16+quad*4+r, col = nt*16+l16)
    const int toff = (w * 16 + quad * 4) * 64 + l16;

    // mask bits for this thread's 4 q-rows
    float4 mv = *reinterpret_cast<const float4*>(maskp + bn * 64 + w * 16 + quad * 4);
    bool bm[4] = {mv.x > 0.5f, mv.y > 0.5f, mv.z > 0.5f, mv.w > 0.5f};

    // res double-buffer; prefetch head 0 now (lands under projections)
    float rA[4][4], rB[4][4];
    {
        const float* rp = res + (((size_t)(bn * 4)) << 12) + toff;
#pragma unroll
        for (int nt = 0; nt < 4; ++nt)
#pragma unroll
            for (int r = 0; r < 4; ++r)
                rA[nt][r] = rp[r * 64 + nt * 16];
    }

    // packed Q (C[e][q] layout): per e-tile (= head) 2 u32 of bf16x2
    unsigned qpk[4][2];

    // ---------------- Projections: Q (swapped, scaled 1/4), K, V ----------------
#pragma unroll 1
    for (int pj = 0; pj < 3; ++pj) {
        const float* Xs = (pj == 0) ? Xq : (pj == 1) ? Xk : Xv;
        const float* Ws = (pj == 0) ? Wq : (pj == 1) ? Wk : Wv;
        // X A-frags direct from global: lane holds X[m=w*16+l16][k=quad*8+ki*32 ..+7]
        const float* p = Xs + base64 + (w * 16 + l16) * 64 + quad * 8;
        float4 x0 = *(const float4*)(p);      float4 x1 = *(const float4*)(p + 4);
        float4 x2 = *(const float4*)(p + 32); float4 x3 = *(const float4*)(p + 36);
        stage_B(Ws, sWA, tid);
        __syncthreads();
        s16x8 a0 = cvt8(x0, x1);
        s16x8 a1 = cvt8(x2, x3);
#pragma unroll
        for (int nt = 0; nt < 4; ++nt) {
            f32x4 acc = {0.f, 0.f, 0.f, 0.f};
            s16x8 b0 = ldfrag(sWA + (swz((nt * 2 + 0) * 64 + lane) << 3));
            s16x8 b1 = ldfrag(sWA + (swz((nt * 2 + 1) * 64 + lane) << 3));
            if (pj == 0) {
                // swapped: D[e][q] = sum_f Wq[f][e] * X[q][f]
                acc = __builtin_amdgcn_mfma_f32_16x16x32_bf16(b0, a0, acc, 0, 0, 0);
                acc = __builtin_amdgcn_mfma_f32_16x16x32_bf16(b1, a1, acc, 0, 0, 0);
                // lane (quad,l16) holds Q[q=w*16+l16][e=nt*16+quad*4+r]; pack *0.25
                qpk[nt][0] = (unsigned)f2bf(acc[0] * 0.25f)
                           | ((unsigned)f2bf(acc[1] * 0.25f) << 16);
                qpk[nt][1] = (unsigned)f2bf(acc[2] * 0.25f)
                           | ((unsigned)f2bf(acc[3] * 0.25f) << 16);
            } else {
                acc = __builtin_amdgcn_mfma_f32_16x16x32_bf16(a0, b0, acc, 0, 0, 0);
                acc = __builtin_amdgcn_mfma_f32_16x16x32_bf16(a1, b1, acc, 0, 0, 0);
                if (pj == 1) {      // K -> scores B-frag layout
#pragma unroll
                    for (int r = 0; r < 4; ++r) {
                        int rowk = (nt * 4 + w) * 32 + ((l16 >> 3) << 4) + quad * 4 + r;
                        sKf[(swz(rowk) << 3) + (l16 & 7)] = f2bf(acc[r]);
                    }
                } else {            // V -> PV B-frag layout (nt == head)
#pragma unroll
                    for (int r = 0; r < 4; ++r) {
                        int kk = w * 16 + quad * 4 + r;
                        int rowv = (nt * 2 + (kk >> 5)) * 64 + (((kk >> 3) & 3) << 4) + l16;
                        sVf[(swz(rowv) << 3) + (kk & 7)] = f2bf(acc[r]);
                    }
                }
            }
        }
        __syncthreads();
    }

    // ---------------- Attention (q-row-tiled; 1 cheap barrier/head) ----------------
    f32x4 ctx[4];
#pragma unroll
    for (int h = 0; h < 4; ++h) ctx[h] = {0.f, 0.f, 0.f, 0.f};

    const s16x8 zf = {0, 0, 0, 0, 0, 0, 0, 0};
#pragma unroll
    for (int h = 0; h < 4; ++h) {
        const size_t sbase = ((size_t)(bn * 4 + h)) << 12;
        float (&rc)[4][4] = (h & 1) ? rB : rA;   // current head's res
        float (&rn)[4][4] = (h & 1) ? rA : rB;   // next head's res

        // rebuild this head's Q A-frag from packed regs: consumer lane c(<32)
        // element j: Q(q=w*16+(c&15), e=(c>>4)*8+j) lives at producer
        // p = (c&16)*2 + (c&15) (j=0..3) / p+16 (j=4..7), word = j>>1.
        s16x8 aq;
        {
            int p0 = ((lane & 16) << 1) + l16;
            unsigned w0 = __shfl(qpk[h][0], p0, 64);
            unsigned w1 = __shfl(qpk[h][1], p0, 64);
            unsigned w2 = __shfl(qpk[h][0], p0 + 16, 64);
            unsigned w3 = __shfl(qpk[h][1], p0 + 16, 64);
            if (lane >= 32) { w0 = 0; w1 = 0; w2 = 0; w3 = 0; }
            u32x4 uv = {w0, w1, w2, w3};
            aq = __builtin_bit_cast(s16x8, uv);
        }

        // scores rows w*16..+15: res folded in as MFMA C-in. K=16 zero-padded.
        // sr holds the masked scores across the barrier (stores deferred).
        float sr[4][4], Sw[4];
#pragma unroll
        for (int nt = 0; nt < 4; ++nt) {
            s16x8 bk = zf;
            if (lane < 32) bk = ldfrag(sKf + (swz((h * 4 + nt) * 32 + lane) << 3));
            f32x4 cin = {rc[nt][0], rc[nt][1], rc[nt][2], rc[nt][3]};
            f32x4 t = __builtin_amdgcn_mfma_f32_16x16x32_bf16(aq, bk, cin, 0, 0, 0);
            float e = 0.f;
#pragma unroll
            for (int r = 0; r < 4; ++r) {
                float s = bm[r] ? -1e9f : t[r];
                sr[nt][r] = s;
                e += __expf(s);             // masked rows -> exp underflows to 0
            }
            e += __shfl_xor(e, 16, 64);
            e += __shfl_xor(e, 32, 64);
            Sw[nt] = e;                     // per-column partial sum (this wave's 16 q)
        }
        float* wS = (float*)(smem + 24576 + ((h & 1) << 10));
        if (quad == 0) {
#pragma unroll
            for (int nt = 0; nt < 4; ++nt) wS[(nt * 16 + l16) * 4 + w] = Sw[nt];
        }
        __syncthreads();   // drains: only long-ago traffic (prev stores, prev res)

        if (h < 3) {        // next head's res: issued AFTER the barrier -> never
                            // barrier-drained; waits land per-wave at next QK
            const float* rp2 = res + sbase + 4096 + toff;
#pragma unroll
            for (int nt = 0; nt < 4; ++nt)
#pragma unroll
                for (int r = 0; r < 4; ++r)
                    rn[nt][r] = rp2[r * 64 + nt * 16];
        }

        // deferred score stores: drain at NEXT head's barrier (full head runway)
#pragma unroll
        for (int nt = 0; nt < 4; ++nt)
#pragma unroll
            for (int r = 0; r < 4; ++r)
                scores_out[sbase + toff + r * 64 + nt * 16] = sr[nt][r];

        // combine + frag writes (exp recomputed; keeps VGPR under the 6-wave cap)
#pragma unroll
        for (int nt = 0; nt < 4; ++nt) {
            float4 vs = *reinterpret_cast<float4*>(&wS[(nt * 16 + l16) * 4]);
            float inv = 1.0f / (vs.x + vs.y + vs.z + vs.w);
            int k  = nt * 16 + l16;
            int rw = (w * 2 + (k >> 5)) * 64 + (((k >> 3) & 3) << 4) + quad * 4;
#pragma unroll
            for (int r = 0; r < 4; ++r)
                sWA[(swz(rw + r) << 3) + (k & 7)] = f2bf(__expf(sr[nt][r]) * inv);
        }
        // PV immediately: same-wave ds write->read + per-wave-private rows,
        // no barrier needed
#pragma unroll
        for (int ki = 0; ki < 2; ++ki) {
            s16x8 ap = ldfrag(sWA + (swz((w * 2 + ki) * 64 + lane) << 3));
            s16x8 bv = ldfrag(sVf + (swz((h * 2 + ki) * 64 + lane) << 3));
            ctx[h] = __builtin_amdgcn_mfma_f32_16x16x32_bf16(ap, bv, ctx[h], 0, 0, 0);
        }
    }
    __syncthreads();   // all attention LDS reads done; sKf/sWA reusable

    // ---------------- fc + residual + layernorm ----------------
    // xres/LN loads issued here; latency hides under ds writes + Wfc staging
    float xres[4][4], scl[4], bia[4];
    {
        const float* xp = Xq + base64 + toff;
#pragma unroll
        for (int nt = 0; nt < 4; ++nt) {
#pragma unroll
            for (int r = 0; r < 4; ++r) xres[nt][r] = xp[r * 64 + nt * 16];
            scl[nt] = lnS[nt * 16 + l16];
            bia[nt] = lnB[nt * 16 + l16];
        }
    }
    // ctx -> fc A-frag layout into sKf (dead); Wfc B-frags into sWA (dead)
#pragma unroll
    for (int hh = 0; hh < 4; ++hh) {
        int c    = hh * 16 + l16;
        int rowb = (w * 2 + (c >> 5)) * 64 + (((c >> 3) & 3) << 4) + quad * 4;
#pragma unroll
        for (int r = 0; r < 4; ++r)
            sKf[(swz(rowb + r) << 3) + (c & 7)] = f2bf(ctx[hh][r]);
    }
    stage_B(Wfc, sWA, tid);
    __syncthreads();

    f32x4 oacc[4];
    {
        s16x8 a0 = ldfrag(sKf + (swz((w * 2 + 0) * 64 + lane) << 3));
        s16x8 a1 = ldfrag(sKf + (swz((w * 2 + 1) * 64 + lane) << 3));
#pragma unroll
        for (int nt = 0; nt < 4; ++nt) {
            f32x4 a = {0.f, 0.f, 0.f, 0.f};
            s16x8 b0 = ldfrag(sWA + (swz((nt * 2 + 0) * 64 + lane) << 3));
            s16x8 b1 = ldfrag(sWA + (swz((nt * 2 + 1) * 64 + lane) << 3));
            a = __builtin_amdgcn_mfma_f32_16x16x32_bf16(a0, b0, a, 0, 0, 0);
            a = __builtin_amdgcn_mfma_f32_16x16x32_bf16(a1, b1, a, 0, 0, 0);
            oacc[nt] = a;
        }
    }

#pragma unroll
    for (int r = 0; r < 4; ++r) {
        float px[4], sum = 0.f, sq = 0.f;
#pragma unroll
        for (int nt = 0; nt < 4; ++nt) {
            float x = oacc[nt][r] + xres[nt][r];
            px[nt] = x; sum += x; sq += x * x;
        }
#pragma unroll
        for (int m = 1; m <= 8; m <<= 1) {
            sum += __shfl_xor(sum, m, 64);
            sq  += __shfl_xor(sq,  m, 64);
        }
        float mu   = sum * 0.015625f;
        float var  = sq * 0.015625f - mu * mu;
        float rstd = rsqrtf(var + 1e-5f);
#pragma unroll
        for (int nt = 0; nt < 4; ++nt) {
            out[base64 + toff + r * 64 + nt * 16] = (px[nt] - mu) * rstd * scl[nt] + bia[nt];
        }
    }
}

extern "C" void kernel_launch(void* const* d_in, const int* in_sizes, int n_in,
                              void* d_out, int out_size, void* d_ws, size_t ws_size,
                              hipStream_t stream) {
    const float* Xq   = (const float*)d_in[0];
    const float* Xk   = (const float*)d_in[1];
    const float* Xv   = (const float*)d_in[2];
    const float* msk  = (const float*)d_in[3];
    const float* res  = (const float*)d_in[4];
    const float* Wq   = (const float*)d_in[5];
    const float* Wk   = (const float*)d_in[6];
    const float* Wv   = (const float*)d_in[7];
    const float* Wfc  = (const float*)d_in[8];
    const float* lnS  = (const float*)d_in[9];
    const float* lnB  = (const float*)d_in[10];
    float* out    = (float*)d_out;
    float* scores = out + OUT_ELEMS;
    mta_kernel<<<BN, 256, 0, stream>>>(Xq, Xk, Xv, msk, res, Wq, Wk, Wv, Wfc,
                                       lnS, lnB, out, scores);
}

// Round 10
// 103.092 us; speedup vs baseline: 1.0534x; 1.0534x over previous
//
#include <hip/hip_runtime.h>

#define B_   8
#define N_   307
#define BN   (B_ * N_)          // 2456 blocks
#define OUT_ELEMS (BN * 64 * 64)

typedef float f32x4 __attribute__((ext_vector_type(4)));
typedef short s16x8 __attribute__((ext_vector_type(8)));

__device__ __forceinline__ unsigned short f2bf(float x) {
    unsigned int u = __builtin_bit_cast(unsigned int, x);
    u += 0x7FFFu + ((u >> 16) & 1u);        // round-to-nearest-even
    return (unsigned short)(u >> 16);
}

// XOR-swizzle on 16B frag rows (G4 / m201): bijective within 8-row groups.
__device__ __forceinline__ int swz(int row) { return row ^ ((row >> 3) & 7); }

__device__ __forceinline__ s16x8 ldfrag(const unsigned short* p) {
    return *reinterpret_cast<const s16x8*>(p);
}

__device__ __forceinline__ s16x8 cvt8(float4 lo, float4 hi) {
    s16x8 f;
    f[0] = (short)f2bf(lo.x); f[1] = (short)f2bf(lo.y);
    f[2] = (short)f2bf(lo.z); f[3] = (short)f2bf(lo.w);
    f[4] = (short)f2bf(hi.x); f[5] = (short)f2bf(hi.y);
    f[6] = (short)f2bf(hi.z); f[7] = (short)f2bf(hi.w);
    return f;
}

// 64x64 row-major fp32 (K x N) global -> bf16 B-operand frag layout (swizzled)
__device__ __forceinline__ void stage_B(const float* __restrict__ src,
                                        unsigned short* dst, int tid) {
    const float4* s4 = reinterpret_cast<const float4*>(src);
#pragma unroll
    for (int i = 0; i < 4; ++i) {
        int idx = i * 256 + tid;
        float4 v = s4[idx];
        int k  = idx >> 4;
        int n0 = (idx & 15) << 2;
        int ki = k >> 5;
        int qd = (k >> 3) & 3;
        int j  = k & 7;
        float vv[4] = {v.x, v.y, v.z, v.w};
#pragma unroll
        for (int c = 0; c < 4; ++c) {
            int n = n0 + c;
            int row = ((n >> 4) * 2 + ki) * 64 + (qd << 4) + (n & 15);
            dst[(swz(row) << 3) + j] = f2bf(vv[c]);
        }
    }
}

__global__ __launch_bounds__(256, 4) void mta_kernel(
    const float* __restrict__ Xq, const float* __restrict__ Xk,
    const float* __restrict__ Xv, const float* __restrict__ maskp,
    const float* __restrict__ res, const float* __restrict__ Wq,
    const float* __restrict__ Wk, const float* __restrict__ Wv,
    const float* __restrict__ Wfc, const float* __restrict__ lnS,
    const float* __restrict__ lnB, float* __restrict__ out,
    float* __restrict__ scores_out)
{
    // 40KB LDS. Attention computes the TRANSPOSED score tile via swapped MFMA:
    //   D[k][q] = mfma(A=K_frag, B=Q_frag, C=res^T)
    // so each lane holds 4 CONSECUTIVE k for one q:
    //   - res loads + score stores are float4 (4 VMEM ops/head vs 16 scalar)
    //   - softmax-over-q is fully in-wave (in-reg over nt + shfl_xor 1,2,4,8
    //     over l16); normalizer is lane-local -> NO cross-wave combine, no wS
    //   - PV A-frag writes are short4 (4 vs 16 scalar)
    // Attn frag buffers ping-pong (sW0/sW1) -> 1 barrier/head: head h+2's
    // writes to buf[h&1] are ordered after head h's PV reads by barrier h+1.
    __shared__ __align__(16) unsigned char smem[40960];
    unsigned short* sKf = (unsigned short*)(smem);           // 8KB K B-frags / ctx frags (fc)
    unsigned short* sQf = (unsigned short*)(smem + 8192);    // 8KB Q B-frags
    unsigned short* sVf = (unsigned short*)(smem + 16384);   // 8KB V B-frags
    unsigned short* sW0 = (unsigned short*)(smem + 24576);   // 8KB proj W / attn frags ping / Wfc (fc)
    unsigned short* sW1 = (unsigned short*)(smem + 32768);   // 8KB attn frags pong

    const int bn   = blockIdx.x;
    const int tid  = threadIdx.x;
    const int w    = tid >> 6;
    const int lane = tid & 63;
    const int quad = lane >> 4;
    const int l16  = lane & 15;
    const size_t base64 = (size_t)bn * 4096;

    // S^T lane geometry: q = nt*16 + l16, k = w*16 + quad*4 + r  (r = 0..3)
    const int soff0 = l16 * 64 + w * 16 + quad * 4;   // + nt*1024 per q-tile

    // mask per lane-q (one bool per nt)
    bool bmv[4];
#pragma unroll
    for (int nt = 0; nt < 4; ++nt)
        bmv[nt] = maskp[bn * 64 + nt * 16 + l16] > 0.5f;

    // res^T float4 prefetch for head 0 (lands under projections)
    f32x4 rA[4];
    {
        const float* rp = res + (((size_t)(bn * 4)) << 12) + soff0;
#pragma unroll
        for (int nt = 0; nt < 4; ++nt)
            rA[nt] = *reinterpret_cast<const f32x4*>(rp + nt * 1024);
    }

    // ---------------- Projections: Q (scaled 1/4), K, V ----------------
#pragma unroll 1
    for (int pj = 0; pj < 3; ++pj) {
        const float* Xs = (pj == 0) ? Xq : (pj == 1) ? Xk : Xv;
        const float* Ws = (pj == 0) ? Wq : (pj == 1) ? Wk : Wv;
        // A-frags direct from global: lane holds X[m=w*16+l16][k=quad*8+ki*32 ..+7]
        const float* p = Xs + base64 + (w * 16 + l16) * 64 + quad * 8;
        float4 x0 = *(const float4*)(p);      float4 x1 = *(const float4*)(p + 4);
        float4 x2 = *(const float4*)(p + 32); float4 x3 = *(const float4*)(p + 36);
        stage_B(Ws, sW0, tid);
        __syncthreads();
        s16x8 a0 = cvt8(x0, x1);
        s16x8 a1 = cvt8(x2, x3);
#pragma unroll
        for (int nt = 0; nt < 4; ++nt) {
            f32x4 acc = {0.f, 0.f, 0.f, 0.f};
            s16x8 b0 = ldfrag(sW0 + (swz((nt * 2 + 0) * 64 + lane) << 3));
            s16x8 b1 = ldfrag(sW0 + (swz((nt * 2 + 1) * 64 + lane) << 3));
            acc = __builtin_amdgcn_mfma_f32_16x16x32_bf16(a0, b0, acc, 0, 0, 0);
            acc = __builtin_amdgcn_mfma_f32_16x16x32_bf16(a1, b1, acc, 0, 0, 0);
            if (pj == 0) {          // Q -> B-frag layout, fold 1/sqrt(16)
#pragma unroll
                for (int r = 0; r < 4; ++r) {
                    int rowq = (nt * 4 + w) * 32 + ((l16 >> 3) << 4) + quad * 4 + r;
                    sQf[(swz(rowq) << 3) + (l16 & 7)] = f2bf(acc[r] * 0.25f);
                }
            } else if (pj == 1) {   // K -> B-frag layout
#pragma unroll
                for (int r = 0; r < 4; ++r) {
                    int rowk = (nt * 4 + w) * 32 + ((l16 >> 3) << 4) + quad * 4 + r;
                    sKf[(swz(rowk) << 3) + (l16 & 7)] = f2bf(acc[r]);
                }
            } else {                // V -> PV B-frag layout (nt == head)
#pragma unroll
                for (int r = 0; r < 4; ++r) {
                    int kk = w * 16 + quad * 4 + r;
                    int rowv = (nt * 2 + (kk >> 5)) * 64 + (((kk >> 3) & 3) << 4) + l16;
                    sVf[(swz(rowv) << 3) + (kk & 7)] = f2bf(acc[r]);
                }
            }
        }
        __syncthreads();
    }

    // ---------------- Attention (S^T tiles; 1 barrier/head) ----------------
    f32x4 ctx[4];
#pragma unroll
    for (int h = 0; h < 4; ++h) ctx[h] = {0.f, 0.f, 0.f, 0.f};

    const s16x8 zf = {0, 0, 0, 0, 0, 0, 0, 0};
#pragma unroll
    for (int h = 0; h < 4; ++h) {
        const size_t sbase = ((size_t)(bn * 4 + h)) << 12;
        unsigned short* buf = (h & 1) ? sW1 : sW0;

        // A-frag: this wave's K tile (k rows w*16..+15). K=16 zero-padded.
        s16x8 bk = zf;
        if (lane < 32) bk = ldfrag(sKf + (swz((h * 4 + w) * 32 + lane) << 3));

        // S^T tiles (kt=w, qt=nt): res^T as MFMA C-in (free adds)
        f32x4 sr[4];
        float esum[4] = {0.f, 0.f, 0.f, 0.f};
#pragma unroll
        for (int nt = 0; nt < 4; ++nt) {
            s16x8 aq = zf;
            if (lane < 32) aq = ldfrag(sQf + (swz((h * 4 + nt) * 32 + lane) << 3));
            f32x4 t = __builtin_amdgcn_mfma_f32_16x16x32_bf16(bk, aq, rA[nt], 0, 0, 0);
#pragma unroll
            for (int r = 0; r < 4; ++r) {
                float s = bmv[nt] ? -1e9f : t[r];
                sr[nt][r] = s;
                esum[r] += __expf(s);   // colsum[k]: accumulate over q-tiles
            }
        }
        // finish colsum over the 16 q of each tile (within-quad lane reduce)
#pragma unroll
        for (int m = 1; m <= 8; m <<= 1)
#pragma unroll
            for (int r = 0; r < 4; ++r)
                esum[r] += __shfl_xor(esum[r], m, 64);
        float inv[4];
#pragma unroll
        for (int r = 0; r < 4; ++r) inv[r] = 1.0f / (esum[r] + 1e-30f);

        // attn -> PV A-frag layout: one short4 per q-tile (4 consecutive j)
#pragma unroll
        for (int nt = 0; nt < 4; ++nt) {
            int row = (nt * 2 + (w >> 1)) * 64 + (((w & 1) << 1) + (quad >> 1)) * 16 + l16;
            short4 pk;
            pk.x = (short)f2bf(__expf(sr[nt][0]) * inv[0]);
            pk.y = (short)f2bf(__expf(sr[nt][1]) * inv[1]);
            pk.z = (short)f2bf(__expf(sr[nt][2]) * inv[2]);
            pk.w = (short)f2bf(__expf(sr[nt][3]) * inv[3]);
            *reinterpret_cast<short4*>(buf + (swz(row) << 3) + ((quad & 1) << 2)) = pk;
        }
        __syncthreads();   // the head's single barrier (frags visible to all)

        if (h < 3) {       // next head's res^T: float4, never barrier-drained
            const float* rp2 = res + sbase + 4096 + soff0;
#pragma unroll
            for (int nt = 0; nt < 4; ++nt)
                rA[nt] = *reinterpret_cast<const f32x4*>(rp2 + nt * 1024);
        }
        // deferred masked-score stores: float4, drain at next head's barrier
#pragma unroll
        for (int nt = 0; nt < 4; ++nt)
            *reinterpret_cast<f32x4*>(scores_out + sbase + soff0 + nt * 1024) = sr[nt];

        // PV: wave w owns q rows w*16..+15 (mt = w)
#pragma unroll
        for (int ki = 0; ki < 2; ++ki) {
            s16x8 ap = ldfrag(buf + (swz((w * 2 + ki) * 64 + lane) << 3));
            s16x8 bv = ldfrag(sVf + (swz((h * 2 + ki) * 64 + lane) << 3));
            ctx[h] = __builtin_amdgcn_mfma_f32_16x16x32_bf16(ap, bv, ctx[h], 0, 0, 0);
        }
        // no post-PV barrier: head h+2's buf reuse is ordered by barrier h+1
    }
    __syncthreads();   // all attention LDS reads done; sKf/sW0 reusable

    // ---------------- fc + residual + layernorm ----------------
    const int toff = (w * 16 + quad * 4) * 64 + l16;
    float xres[4][4], scl[4], bia[4];
    {
        const float* xp = Xq + base64 + toff;
#pragma unroll
        for (int nt = 0; nt < 4; ++nt) {
#pragma unroll
            for (int r = 0; r < 4; ++r) xres[nt][r] = xp[r * 64 + nt * 16];
            scl[nt] = lnS[nt * 16 + l16];
            bia[nt] = lnB[nt * 16 + l16];
        }
    }
    // ctx -> fc A-frag layout into sKf (dead); Wfc B-frags into sW0 (dead)
#pragma unroll
    for (int hh = 0; hh < 4; ++hh) {
        int c    = hh * 16 + l16;
        int rowb = (w * 2 + (c >> 5)) * 64 + (((c >> 3) & 3) << 4) + quad * 4;
#pragma unroll
        for (int r = 0; r < 4; ++r)
            sKf[(swz(rowb + r) << 3) + (c & 7)] = f2bf(ctx[hh][r]);
    }
    stage_B(Wfc, sW0, tid);
    __syncthreads();

    f32x4 oacc[4];
    {
        s16x8 a0 = ldfrag(sKf + (swz((w * 2 + 0) * 64 + lane) << 3));
        s16x8 a1 = ldfrag(sKf + (swz((w * 2 + 1) * 64 + lane) << 3));
#pragma unroll
        for (int nt = 0; nt < 4; ++nt) {
            f32x4 a = {0.f, 0.f, 0.f, 0.f};
            s16x8 b0 = ldfrag(sW0 + (swz((nt * 2 + 0) * 64 + lane) << 3));
            s16x8 b1 = ldfrag(sW0 + (swz((nt * 2 + 1) * 64 + lane) << 3));
            a = __builtin_amdgcn_mfma_f32_16x16x32_bf16(a0, b0, a, 0, 0, 0);
            a = __builtin_amdgcn_mfma_f32_16x16x32_bf16(a1, b1, a, 0, 0, 0);
            oacc[nt] = a;
        }
    }

#pragma unroll
    for (int r = 0; r < 4; ++r) {
        float px[4], sum = 0.f, sq = 0.f;
#pragma unroll
        for (int nt = 0; nt < 4; ++nt) {
            float x = oacc[nt][r] + xres[nt][r];
            px[nt] = x; sum += x; sq += x * x;
        }
#pragma unroll
        for (int m = 1; m <= 8; m <<= 1) {
            sum += __shfl_xor(sum, m, 64);
            sq  += __shfl_xor(sq,  m, 64);
        }
        float mu   = sum * 0.015625f;
        float var  = sq * 0.015625f - mu * mu;
        float rstd = rsqrtf(var + 1e-5f);
#pragma unroll
        for (int nt = 0; nt < 4; ++nt) {
            out[base64 + toff + r * 64 + nt * 16] = (px[nt] - mu) * rstd * scl[nt] + bia[nt];
        }
    }
}

extern "C" void kernel_launch(void* const* d_in, const int* in_sizes, int n_in,
                              void* d_out, int out_size, void* d_ws, size_t ws_size,
                              hipStream_t stream) {
    const float* Xq   = (const float*)d_in[0];
    const float* Xk   = (const float*)d_in[1];
    const float* Xv   = (const float*)d_in[2];
    const float* msk  = (const float*)d_in[3];
    const float* res  = (const float*)d_in[4];
    const float* Wq   = (const float*)d_in[5];
    const float* Wk   = (const float*)d_in[6];
    const float* Wv   = (const float*)d_in[7];
    const float* Wfc  = (const float*)d_in[8];
    const float* lnS  = (const float*)d_in[9];
    const float* lnB  = (const float*)d_in[10];
    float* out    = (float*)d_out;
    float* scores = out + OUT_ELEMS;
    mta_kernel<<<BN, 256, 0, stream>>>(Xq, Xk, Xv, msk, res, Wq, Wk, Wv, Wfc,
                                       lnS, lnB, out, scores);
}

// Round 11
// 102.682 us; speedup vs baseline: 1.0576x; 1.0040x over previous
//
#include <hip/hip_runtime.h>

#define B_   8
#define N_   307
#define BN   (B_ * N_)          // 2456 blocks
#define OUT_ELEMS (BN * 64 * 64)

typedef float f32x4 __attribute__((ext_vector_type(4)));
typedef short s16x8 __attribute__((ext_vector_type(8)));

__device__ __forceinline__ unsigned short f2bf(float x) {
    unsigned int u = __builtin_bit_cast(unsigned int, x);
    u += 0x7FFFu + ((u >> 16) & 1u);        // round-to-nearest-even
    return (unsigned short)(u >> 16);
}

// XOR-swizzle on 16B frag rows (G4 / m201): bijective within 8-row groups.
__device__ __forceinline__ int swz(int row) { return row ^ ((row >> 3) & 7); }

__device__ __forceinline__ s16x8 ldfrag(const unsigned short* p) {
    return *reinterpret_cast<const s16x8*>(p);
}

__device__ __forceinline__ s16x8 cvt8(float4 lo, float4 hi) {
    s16x8 f;
    f[0] = (short)f2bf(lo.x); f[1] = (short)f2bf(lo.y);
    f[2] = (short)f2bf(lo.z); f[3] = (short)f2bf(lo.w);
    f[4] = (short)f2bf(hi.x); f[5] = (short)f2bf(hi.y);
    f[6] = (short)f2bf(hi.z); f[7] = (short)f2bf(hi.w);
    return f;
}

// W loads split into issue (loadW -> regs) and LDS write (writeW), so the
// global latency can hide under the PREVIOUS projection's MFMA phase (T14).
__device__ __forceinline__ void loadW(const float* __restrict__ src,
                                      float4 wvv[4], int tid) {
    const float4* s4 = reinterpret_cast<const float4*>(src);
#pragma unroll
    for (int i = 0; i < 4; ++i) wvv[i] = s4[i * 256 + tid];
}

// regs (64x64 row-major fp32 K x N) -> bf16 B-operand frag layout (swizzled)
__device__ __forceinline__ void writeW(const float4 wvv[4],
                                       unsigned short* dst, int tid) {
#pragma unroll
    for (int i = 0; i < 4; ++i) {
        int idx = i * 256 + tid;
        float4 v = wvv[i];
        int k  = idx >> 4;
        int n0 = (idx & 15) << 2;
        int ki = k >> 5;
        int qd = (k >> 3) & 3;
        int j  = k & 7;
        float vv[4] = {v.x, v.y, v.z, v.w};
#pragma unroll
        for (int c = 0; c < 4; ++c) {
            int n = n0 + c;
            int row = ((n >> 4) * 2 + ki) * 64 + (qd << 4) + (n & 15);
            dst[(swz(row) << 3) + j] = f2bf(vv[c]);
        }
    }
}

__global__ __launch_bounds__(256, 4) void mta_kernel(
    const float* __restrict__ Xq, const float* __restrict__ Xk,
    const float* __restrict__ Xv, const float* __restrict__ maskp,
    const float* __restrict__ res, const float* __restrict__ Wq,
    const float* __restrict__ Wk, const float* __restrict__ Wv,
    const float* __restrict__ Wfc, const float* __restrict__ lnS,
    const float* __restrict__ lnB, float* __restrict__ out,
    float* __restrict__ scores_out)
{
    // R10 layouts kept byte-identical (S^T attention, float4 res/scores,
    // short4 PV frags, ping-pong attn buffers). This round: software-pipeline
    // the projection/fc load chains (each phase issues the NEXT phase's W+X at
    // its top; barriers only drain phase-old loads) and keep exp values in
    // regs across the head barrier (no recompute).
    __shared__ __align__(16) unsigned char smem[40960];
    unsigned short* sKf = (unsigned short*)(smem);           // 8KB K B-frags / ctx frags (fc)
    unsigned short* sQf = (unsigned short*)(smem + 8192);    // 8KB Q B-frags
    unsigned short* sVf = (unsigned short*)(smem + 16384);   // 8KB V B-frags
    unsigned short* sW0 = (unsigned short*)(smem + 24576);   // 8KB proj W ping / attn ping / Wfc (fc)
    unsigned short* sW1 = (unsigned short*)(smem + 32768);   // 8KB proj W pong / attn pong

    const int bn   = blockIdx.x;
    const int tid  = threadIdx.x;
    const int w    = tid >> 6;
    const int lane = tid & 63;
    const int quad = lane >> 4;
    const int l16  = lane & 15;
    const size_t base64 = (size_t)bn * 4096;

    // S^T lane geometry: q = nt*16 + l16, k = w*16 + quad*4 + r  (r = 0..3)
    const int soff0 = l16 * 64 + w * 16 + quad * 4;   // + nt*1024 per q-tile

    // mask per lane-q (one bool per nt)
    bool bmv[4];
#pragma unroll
    for (int nt = 0; nt < 4; ++nt)
        bmv[nt] = maskp[bn * 64 + nt * 16 + l16] > 0.5f;

    // ---------------- Projections (pipelined): Q (scaled 1/4), K, V ----------------
    const int xoff = (w * 16 + l16) * 64 + quad * 8;
    float4 wv[4];
    loadW(Wq, wv, tid);                                  // W for pj0
    const float* pX0 = Xq + base64 + xoff;               // X for pj0
    float4 x00 = *(const float4*)(pX0),      x01 = *(const float4*)(pX0 + 4);
    float4 x02 = *(const float4*)(pX0 + 32), x03 = *(const float4*)(pX0 + 36);
    // res^T float4 prefetch for head 0 (lands under projections)
    f32x4 rA[4];
    {
        const float* rp = res + (((size_t)(bn * 4)) << 12) + soff0;
#pragma unroll
        for (int nt = 0; nt < 4; ++nt)
            rA[nt] = *reinterpret_cast<const f32x4*>(rp + nt * 1024);
    }
    writeW(wv, sW0, tid);                                // waits Wq only
    __syncthreads();                                     // B1

    // ---- pj0 (Q): issue pj1's W+X at top, then compute
    loadW(Wk, wv, tid);
    const float* pX1 = Xk + base64 + xoff;
    float4 x10 = *(const float4*)(pX1),      x11 = *(const float4*)(pX1 + 4);
    float4 x12 = *(const float4*)(pX1 + 32), x13 = *(const float4*)(pX1 + 36);
    {
        s16x8 a0 = cvt8(x00, x01);
        s16x8 a1 = cvt8(x02, x03);
#pragma unroll
        for (int nt = 0; nt < 4; ++nt) {
            f32x4 acc = {0.f, 0.f, 0.f, 0.f};
            s16x8 b0 = ldfrag(sW0 + (swz((nt * 2 + 0) * 64 + lane) << 3));
            s16x8 b1 = ldfrag(sW0 + (swz((nt * 2 + 1) * 64 + lane) << 3));
            acc = __builtin_amdgcn_mfma_f32_16x16x32_bf16(a0, b0, acc, 0, 0, 0);
            acc = __builtin_amdgcn_mfma_f32_16x16x32_bf16(a1, b1, acc, 0, 0, 0);
#pragma unroll
            for (int r = 0; r < 4; ++r) {    // Q -> B-frag layout, fold 1/sqrt(16)
                int rowq = (nt * 4 + w) * 32 + ((l16 >> 3) << 4) + quad * 4 + r;
                sQf[(swz(rowq) << 3) + (l16 & 7)] = f2bf(acc[r] * 0.25f);
            }
        }
    }
    writeW(wv, sW1, tid);                                // Wk: issued a phase ago
    __syncthreads();                                     // B2

    // ---- pj1 (K): issue pj2's W+X at top
    loadW(Wv, wv, tid);
    const float* pX2 = Xv + base64 + xoff;
    float4 x20 = *(const float4*)(pX2),      x21 = *(const float4*)(pX2 + 4);
    float4 x22 = *(const float4*)(pX2 + 32), x23 = *(const float4*)(pX2 + 36);
    {
        s16x8 a0 = cvt8(x10, x11);
        s16x8 a1 = cvt8(x12, x13);
#pragma unroll
        for (int nt = 0; nt < 4; ++nt) {
            f32x4 acc = {0.f, 0.f, 0.f, 0.f};
            s16x8 b0 = ldfrag(sW1 + (swz((nt * 2 + 0) * 64 + lane) << 3));
            s16x8 b1 = ldfrag(sW1 + (swz((nt * 2 + 1) * 64 + lane) << 3));
            acc = __builtin_amdgcn_mfma_f32_16x16x32_bf16(a0, b0, acc, 0, 0, 0);
            acc = __builtin_amdgcn_mfma_f32_16x16x32_bf16(a1, b1, acc, 0, 0, 0);
#pragma unroll
            for (int r = 0; r < 4; ++r) {    // K -> B-frag layout
                int rowk = (nt * 4 + w) * 32 + ((l16 >> 3) << 4) + quad * 4 + r;
                sKf[(swz(rowk) << 3) + (l16 & 7)] = f2bf(acc[r]);
            }
        }
    }
    writeW(wv, sW0, tid);                                // Wv: issued a phase ago
    __syncthreads();                                     // B3

    // ---- pj2 (V)
    {
        s16x8 a0 = cvt8(x20, x21);
        s16x8 a1 = cvt8(x22, x23);
#pragma unroll
        for (int nt = 0; nt < 4; ++nt) {
            f32x4 acc = {0.f, 0.f, 0.f, 0.f};
            s16x8 b0 = ldfrag(sW0 + (swz((nt * 2 + 0) * 64 + lane) << 3));
            s16x8 b1 = ldfrag(sW0 + (swz((nt * 2 + 1) * 64 + lane) << 3));
            acc = __builtin_amdgcn_mfma_f32_16x16x32_bf16(a0, b0, acc, 0, 0, 0);
            acc = __builtin_amdgcn_mfma_f32_16x16x32_bf16(a1, b1, acc, 0, 0, 0);
#pragma unroll
            for (int r = 0; r < 4; ++r) {    // V -> PV B-frag layout (nt == head)
                int kk = w * 16 + quad * 4 + r;
                int rowv = (nt * 2 + (kk >> 5)) * 64 + (((kk >> 3) & 3) << 4) + l16;
                sVf[(swz(rowv) << 3) + (kk & 7)] = f2bf(acc[r]);
            }
        }
    }
    __syncthreads();                                     // B4: frags visible

    // ---------------- Attention (S^T tiles; 1 barrier/head) ----------------
    f32x4 ctx[4];
#pragma unroll
    for (int h = 0; h < 4; ++h) ctx[h] = {0.f, 0.f, 0.f, 0.f};

    float4 wfc[4];                      // fc operands, issued in the h==3 slot
    float xres[4][4], scl[4], bia[4];
    const int toff = (w * 16 + quad * 4) * 64 + l16;

    const s16x8 zf = {0, 0, 0, 0, 0, 0, 0, 0};
#pragma unroll
    for (int h = 0; h < 4; ++h) {
        const size_t sbase = ((size_t)(bn * 4 + h)) << 12;
        unsigned short* buf = (h & 1) ? sW1 : sW0;

        // A-frag: this wave's K tile (k rows w*16..+15). K=16 zero-padded.
        s16x8 bk = zf;
        if (lane < 32) bk = ldfrag(sKf + (swz((h * 4 + w) * 32 + lane) << 3));

        // S^T tiles (kt=w, qt=nt): res^T as MFMA C-in (free adds)
        f32x4 sr[4];
        float ev[4][4];                 // exp kept across the barrier
        float esum[4] = {0.f, 0.f, 0.f, 0.f};
#pragma unroll
        for (int nt = 0; nt < 4; ++nt) {
            s16x8 aq = zf;
            if (lane < 32) aq = ldfrag(sQf + (swz((h * 4 + nt) * 32 + lane) << 3));
            f32x4 t = __builtin_amdgcn_mfma_f32_16x16x32_bf16(bk, aq, rA[nt], 0, 0, 0);
#pragma unroll
            for (int r = 0; r < 4; ++r) {
                float s = bmv[nt] ? -1e9f : t[r];
                sr[nt][r] = s;
                float e = __expf(s);    // masked -> underflows to +0
                ev[nt][r] = e;
                esum[r] += e;           // colsum[k] over q-tiles
            }
        }
        // finish colsum over the 16 q of each tile (within-quad lane reduce)
#pragma unroll
        for (int m = 1; m <= 8; m <<= 1)
#pragma unroll
            for (int r = 0; r < 4; ++r)
                esum[r] += __shfl_xor(esum[r], m, 64);
        float inv[4];
#pragma unroll
        for (int r = 0; r < 4; ++r) inv[r] = 1.0f / (esum[r] + 1e-30f);

        // attn -> PV A-frag layout: one short4 per q-tile (4 consecutive j)
#pragma unroll
        for (int nt = 0; nt < 4; ++nt) {
            int row = (nt * 2 + (w >> 1)) * 64 + (((w & 1) << 1) + (quad >> 1)) * 16 + l16;
            short4 pk;
            pk.x = (short)f2bf(ev[nt][0] * inv[0]);
            pk.y = (short)f2bf(ev[nt][1] * inv[1]);
            pk.z = (short)f2bf(ev[nt][2] * inv[2]);
            pk.w = (short)f2bf(ev[nt][3] * inv[3]);
            *reinterpret_cast<short4*>(buf + (swz(row) << 3) + ((quad & 1) << 2)) = pk;
        }
        __syncthreads();   // the head's single barrier (frags visible to all)

        if (h < 3) {       // next head's res^T: float4, never barrier-drained
            const float* rp2 = res + sbase + 4096 + soff0;
#pragma unroll
            for (int nt = 0; nt < 4; ++nt)
                rA[nt] = *reinterpret_cast<const f32x4*>(rp2 + nt * 1024);
        } else {           // h==3 slot: issue fc operands (T14 issue-early)
            loadW(Wfc, wfc, tid);
            const float* xp = Xq + base64 + toff;
#pragma unroll
            for (int nt = 0; nt < 4; ++nt) {
#pragma unroll
                for (int r = 0; r < 4; ++r) xres[nt][r] = xp[r * 64 + nt * 16];
                scl[nt] = lnS[nt * 16 + l16];
                bia[nt] = lnB[nt * 16 + l16];
            }
        }
        // deferred masked-score stores: float4, drain at next head's barrier
#pragma unroll
        for (int nt = 0; nt < 4; ++nt)
            *reinterpret_cast<f32x4*>(scores_out + sbase + soff0 + nt * 1024) = sr[nt];

        // PV: wave w owns q rows w*16..+15 (mt = w)
#pragma unroll
        for (int ki = 0; ki < 2; ++ki) {
            s16x8 ap = ldfrag(buf + (swz((w * 2 + ki) * 64 + lane) << 3));
            s16x8 bv = ldfrag(sVf + (swz((h * 2 + ki) * 64 + lane) << 3));
            ctx[h] = __builtin_amdgcn_mfma_f32_16x16x32_bf16(ap, bv, ctx[h], 0, 0, 0);
        }
        // no post-PV barrier: head h+2's buf reuse is ordered by barrier h+1
    }
    __syncthreads();   // all attention LDS reads done; sKf/sW0 reusable

    // ---------------- fc + residual + layernorm ----------------
    // ctx -> fc A-frag layout into sKf (dead); Wfc B-frags into sW0 (dead);
    // all global operands already in regs (issued during head 3).
#pragma unroll
    for (int hh = 0; hh < 4; ++hh) {
        int c    = hh * 16 + l16;
        int rowb = (w * 2 + (c >> 5)) * 64 + (((c >> 3) & 3) << 4) + quad * 4;
#pragma unroll
        for (int r = 0; r < 4; ++r)
            sKf[(swz(rowb + r) << 3) + (c & 7)] = f2bf(ctx[hh][r]);
    }
    writeW(wfc, sW0, tid);
    __syncthreads();

    f32x4 oacc[4];
    {
        s16x8 a0 = ldfrag(sKf + (swz((w * 2 + 0) * 64 + lane) << 3));
        s16x8 a1 = ldfrag(sKf + (swz((w * 2 + 1) * 64 + lane) << 3));
#pragma unroll
        for (int nt = 0; nt < 4; ++nt) {
            f32x4 a = {0.f, 0.f, 0.f, 0.f};
            s16x8 b0 = ldfrag(sW0 + (swz((nt * 2 + 0) * 64 + lane) << 3));
            s16x8 b1 = ldfrag(sW0 + (swz((nt * 2 + 1) * 64 + lane) << 3));
            a = __builtin_amdgcn_mfma_f32_16x16x32_bf16(a0, b0, a, 0, 0, 0);
            a = __builtin_amdgcn_mfma_f32_16x16x32_bf16(a1, b1, a, 0, 0, 0);
            oacc[nt] = a;
        }
    }

#pragma unroll
    for (int r = 0; r < 4; ++r) {
        float px[4], sum = 0.f, sq = 0.f;
#pragma unroll
        for (int nt = 0; nt < 4; ++nt) {
            float x = oacc[nt][r] + xres[nt][r];
            px[nt] = x; sum += x; sq += x * x;
        }
#pragma unroll
        for (int m = 1; m <= 8; m <<= 1) {
            sum += __shfl_xor(sum, m, 64);
            sq  += __shfl_xor(sq,  m, 64);
        }
        float mu   = sum * 0.015625f;
        float var  = sq * 0.015625f - mu * mu;
        float rstd = rsqrtf(var + 1e-5f);
#pragma unroll
        for (int nt = 0; nt < 4; ++nt) {
            out[base64 + toff + r * 64 + nt * 16] = (px[nt] - mu) * rstd * scl[nt] + bia[nt];
        }
    }
}

extern "C" void kernel_launch(void* const* d_in, const int* in_sizes, int n_in,
                              void* d_out, int out_size, void* d_ws, size_t ws_size,
                              hipStream_t stream) {
    const float* Xq   = (const float*)d_in[0];
    const float* Xk   = (const float*)d_in[1];
    const float* Xv   = (const float*)d_in[2];
    const float* msk  = (const float*)d_in[3];
    const float* res  = (const float*)d_in[4];
    const float* Wq   = (const float*)d_in[5];
    const float* Wk   = (const float*)d_in[6];
    const float* Wv   = (const float*)d_in[7];
    const float* Wfc  = (const float*)d_in[8];
    const float* lnS  = (const float*)d_in[9];
    const float* lnB  = (const float*)d_in[10];
    float* out    = (float*)d_out;
    float* scores = out + OUT_ELEMS;
    mta_kernel<<<BN, 256, 0, stream>>>(Xq, Xk, Xv, msk, res, Wq, Wk, Wv, Wfc,
                                       lnS, lnB, out, scores);
}